// Round 3
// baseline (467.439 us; speedup 1.0000x reference)
//
#include <hip/hip_runtime.h>
#include <math.h>

typedef unsigned long long u64;
typedef unsigned int u32;

#define M_ANCH 360000
#define NCLS 80
#define KTOP 1000
#define CAP 4096
#define NBINS 65536
#define RREP 4
#define CONF_THRESH 0.05f
#define NMS_THRESH 0.6f
#define CTR_CLAMP 32.0f
#define SCALE_CLAMP 4.1351665567423560f  /* log(1000/16) */

/* ---- workspace layout (bytes) ---- */
#define HIST_OFF   0u
#define HIST_BYTES (RREP * NBINS * 4u)          /* 1,048,576 */
#define CNT_OFF    (HIST_OFF + HIST_BYTES)
#define B_OFF      (CNT_OFF + 4u)
#define VW_OFF     (B_OFF + 4u)                 /* 16 u64 = 128 B */
#define ZERO_BYTES (VW_OFF + 128u)
#define CAND_OFF   ZERO_BYTES                   /* 4096 * 8  */
#define SC_OFF     (CAND_OFF + CAP * 8u)        /* M floats  */
#define CLS_OFF    (SC_OFF + M_ANCH * 4u)       /* M ints    */
#define SSC_OFF    (CLS_OFF + M_ANCH * 4u)      /* 1000 floats */
#define SCLS_OFF   (SSC_OFF + KTOP * 4u)        /* 1000 ints */
#define SUP_OFF    (SCLS_OFF + KTOP * 4u)       /* 16000 u64 */

__device__ __forceinline__ u32 fkey(float f) {
    u32 u = __float_as_uint(f);
    return (u & 0x80000000u) ? ~u : (u | 0x80000000u);
}

/* K1: per-anchor max/argmax over 80 classes. 4 lanes per anchor; lane q of
   anchor a reads float4s [5*(4a+q) .. 5*(4a+q)+4] -- 80 contiguous bytes per
   lane, 5 independent loads in flight, then 2-step shuffle-xor reduce. */
#define RED4(v, cb)                                    \
    if (v.x > mv) { mv = v.x; mc = (cb); }             \
    if (v.y > mv) { mv = v.y; mc = (cb) + 1; }         \
    if (v.z > mv) { mv = v.z; mc = (cb) + 2; }         \
    if (v.w > mv) { mv = v.w; mc = (cb) + 3; }

__global__ __launch_bounds__(256) void k_score(const float* __restrict__ cls_pred,
                                               float* __restrict__ sc_all,
                                               int* __restrict__ cls_all,
                                               u32* __restrict__ hist) {
    int i = blockIdx.x * 256 + threadIdx.x;   /* i in [0, 4*M); 4*M % 256 == 0 */
    int q = i & 3;
    const float4* p = (const float4*)cls_pred + (size_t)i * 5;
    float4 v0 = p[0];
    float4 v1 = p[1];
    float4 v2 = p[2];
    float4 v3 = p[3];
    float4 v4 = p[4];
    float mv = -1e30f;
    int mc = 0;
    int cb = 20 * q;
    RED4(v0, cb);
    RED4(v1, cb + 4);
    RED4(v2, cb + 8);
    RED4(v3, cb + 12);
    RED4(v4, cb + 16);
#pragma unroll
    for (int off = 1; off < 4; off <<= 1) {
        float ov = __shfl_xor(mv, off);
        int oc = __shfl_xor(mc, off);
        if (ov > mv || (ov == mv && oc < mc)) { mv = ov; mc = oc; }
    }
    if (q == 0) {
        int a = i >> 2;
        float s = 1.0f / (1.0f + expf(-mv));
        sc_all[a] = s;
        cls_all[a] = mc;
        float m = (s >= CONF_THRESH) ? s : -1.0f;
        u32 u = fkey(m);
        atomicAdd(&hist[((blockIdx.x & (RREP - 1)) << 16) + (u >> 16)], 1u);
    }
}

/* K2: find boundary bin B: bins > B hold < KTOP elements, bins >= B hold >= KTOP */
__global__ __launch_bounds__(1024) void k_scan(u32* __restrict__ hist,
                                               u32* __restrict__ outB) {
    __shared__ u32 csum[1024];
    int t = threadIdx.x;
    int base = t * 64;
    u32 mysum = 0;
#pragma unroll 4
    for (int k = 0; k < 64; k++) {
        u32 b = base + k;
        u32 h = hist[b] + hist[NBINS + b] + hist[2 * NBINS + b] + hist[3 * NBINS + b];
        hist[b] = h;  /* store summed value for the walk below */
        mysum += h;
    }
    csum[t] = mysum;
    __syncthreads();
    u32 v = mysum;
    for (int off = 1; off < 1024; off <<= 1) {
        u32 add = (t + off < 1024) ? csum[t + off] : 0u;
        __syncthreads();
        v += add;
        csum[t] = v;
        __syncthreads();
    }
    u32 A = (t == 1023) ? 0u : csum[t + 1];
    if (A < KTOP && A + mysum >= KTOP) {
        u32 c = A;
        for (int k = 63; k >= 0; k--) {
            u32 b = base + k;
            u32 h = hist[b];
            if (c + h >= KTOP) { outB[0] = b; break; }
            c += h;
        }
    }
}

/* K3: compact candidates (all elements whose key bin >= B) as 64-bit keys.
   Set of candidates is deterministic; arrival order is not, but the sort in
   K4 makes order irrelevant as long as counter never exceeds CAP (4x margin
   over the expected ~1k boundary-bin population). */
__global__ __launch_bounds__(256) void k_compact(const float* __restrict__ sc_all,
                                                 const u32* __restrict__ pB,
                                                 u32* __restrict__ counter,
                                                 u64* __restrict__ cand) {
    int i = blockIdx.x * 256 + threadIdx.x;
    if (i >= M_ANCH) return;
    u32 B = *pB;
    float s = sc_all[i];
    float m = (s >= CONF_THRESH) ? s : -1.0f;
    u32 u = fkey(m);
    if ((u >> 16) >= B) {
        u32 pos = atomicAdd(counter, 1u);
        if (pos < CAP) cand[pos] = ((u64)u << 32) | (u64)(0xFFFFFFFFu - (u32)i);
    }
}

/* K4: adaptive bitonic sort (size P = next pow2 >= n, min 1024), take top
   1000, decode boxes. */
__global__ __launch_bounds__(1024) void k_select(const u64* __restrict__ cand,
                                                 const u32* __restrict__ counter,
                                                 const float* __restrict__ sc_all,
                                                 const int* __restrict__ cls_all,
                                                 const float* __restrict__ reg_pred,
                                                 const float* __restrict__ anchors,
                                                 float* __restrict__ out,
                                                 float* __restrict__ sel_sc,
                                                 int* __restrict__ sel_cls,
                                                 u64* __restrict__ valid_words) {
    __shared__ u64 keys[CAP];
    int t = threadIdx.x;
    u32 n = *counter;
    if (n > CAP) n = CAP;
    u32 P = 1024;
    while (P < n) P <<= 1;            /* P in {1024, 2048, 4096} */
    for (u32 i = t; i < P; i += 1024) keys[i] = (i < n) ? cand[i] : 0ull;
    for (u32 k = 2; k <= P; k <<= 1) {
        for (u32 j = k >> 1; j > 0; j >>= 1) {
            __syncthreads();
            for (u32 i = t; i < P; i += 1024) {
                u32 ixj = i ^ j;
                if (ixj > i) {
                    u64 a = keys[i], b = keys[ixj];
                    bool desc = ((i & k) == 0);
                    if (desc ? (a < b) : (a > b)) { keys[i] = b; keys[ixj] = a; }
                }
            }
        }
    }
    __syncthreads();
    if (t < KTOP) {
        u64 key = keys[t];
        u32 idx = 0xFFFFFFFFu - (u32)(key & 0xFFFFFFFFull);
        if (idx >= M_ANCH) idx = 0;  /* safety; cannot happen for M >= K */
        float s = sc_all[idx];
        int cl = cls_all[idx];
        float4 a = ((const float4*)anchors)[idx];
        float4 r = ((const float4*)reg_pred)[idx];
        float ox = fminf(fmaxf(r.x * a.z, -CTR_CLAMP), CTR_CLAMP);
        float oy = fminf(fmaxf(r.y * a.w, -CTR_CLAMP), CTR_CLAMP);
        float cx = a.x + ox, cy = a.y + oy;
        float ww = a.z * expf(fminf(r.z, SCALE_CLAMP));
        float hh = a.w * expf(fminf(r.w, SCALE_CLAMP));
        float4 box;
        box.x = cx - 0.5f * ww;
        box.y = cy - 0.5f * hh;
        box.z = cx + 0.5f * ww;
        box.w = cy + 0.5f * hh;
        ((float4*)out)[t] = box;                 /* boxes: out[0..3999] */
        out[5 * KTOP + t] = (float)cl;           /* classes: out[5000..5999] */
        sel_sc[t] = s;
        sel_cls[t] = cl;
        if (s >= CONF_THRESH) atomicOr(&valid_words[t >> 6], 1ull << (t & 63));
    }
}

/* K5: suppression matrix — one wave computes one 64-wide word via ballot */
__global__ __launch_bounds__(256) void k_supmat(const float* __restrict__ out,
                                                const int* __restrict__ sel_cls,
                                                u64* __restrict__ sup) {
    int wid = threadIdx.x >> 6;
    int lane = threadIdx.x & 63;
    int g = blockIdx.x * 4 + wid;          /* g in [0, 16000) */
    int i = g >> 4;
    int w = g & 15;
    int j = w * 64 + lane;
    int jc = (j < KTOP) ? j : (KTOP - 1);
    float4 bi = ((const float4*)out)[i];
    float4 bj = ((const float4*)out)[jc];
    int ci = sel_cls[i], cj = sel_cls[jc];
    float ai = (bi.z - bi.x) * (bi.w - bi.y);
    float aj = (bj.z - bj.x) * (bj.w - bj.y);
    float xx1 = fmaxf(bi.x, bj.x), yy1 = fmaxf(bi.y, bj.y);
    float xx2 = fminf(bi.z, bj.z), yy2 = fminf(bi.w, bj.w);
    float iw = fmaxf(1e-28f, xx2 - xx1), ih = fmaxf(1e-28f, yy2 - yy1);
    float inter = iw * ih;
    float iou = inter / (ai + aj - inter + 1e-14f);
    bool pred = (j < i) && (ci == cj) && (iou > NMS_THRESH);
    u64 bal = __ballot((int)pred);
    if (lane == 0) sup[g] = bal;
}

/* K6: sequential greedy NMS scan, single wave; 16 lanes hold keep-mask words */
#define LOADC(cidx, buf)                                                         \
    {                                                                            \
        _Pragma("unroll") for (int r = 0; r < 16; r++) {                         \
            int row = (cidx)*16 + r;                                             \
            buf[r] = (active && row < KTOP) ? sup[row * 16 + lane] : 0ull;       \
        }                                                                        \
    }

#define PROCC(cidx, buf)                                                         \
    {                                                                            \
        _Pragma("unroll") for (int r = 0; r < 16; r++) {                         \
            int i = (cidx)*16 + r;                                               \
            if (i < KTOP) {                                                      \
                u64 x = buf[r] & keepw;                                          \
                int anysup = __any(x != 0ull);                                   \
                u64 vwv = vws[i >> 6];                                           \
                int vi = (int)((vwv >> (i & 63)) & 1ull);                        \
                int ki = (!anysup) && vi;                                        \
                if (lane == (i >> 6) && ki) keepw |= (1ull << (i & 63));         \
            }                                                                    \
        }                                                                        \
    }

__global__ __launch_bounds__(64) void k_nms(const u64* __restrict__ sup,
                                            const u64* __restrict__ valid_words,
                                            const float* __restrict__ sel_sc,
                                            float* __restrict__ out) {
    __shared__ u64 vws[16];
    __shared__ u64 kw[16];
    int lane = threadIdx.x;
    bool active = lane < 16;
    if (active) vws[lane] = valid_words[lane];
    __syncthreads();
    u64 keepw = 0ull;
    u64 bufA[16], bufB[16];
    const int nChunks = (KTOP + 15) / 16;  /* 63 */
    LOADC(0, bufA);
    for (int c = 0; c < nChunks; c += 2) {
        if (c + 1 < nChunks) LOADC(c + 1, bufB);
        PROCC(c, bufA);
        if (c + 2 < nChunks) LOADC(c + 2, bufA);
        if (c + 1 < nChunks) PROCC(c + 1, bufB);
    }
    if (active) kw[lane] = keepw;
    __syncthreads();
    for (int t = lane; t < KTOP; t += 64) {
        int kb = (int)((kw[t >> 6] >> (t & 63)) & 1ull);
        float s = sel_sc[t];
        out[4 * KTOP + t] = kb ? s : 0.0f;   /* scores*keep: out[4000..4999] */
        out[6 * KTOP + t] = (float)kb;       /* keep:        out[6000..6999] */
    }
}

extern "C" void kernel_launch(void* const* d_in, const int* in_sizes, int n_in,
                              void* d_out, int out_size, void* d_ws, size_t ws_size,
                              hipStream_t stream) {
    const float* cls_pred = (const float*)d_in[0];
    const float* reg_pred = (const float*)d_in[1];
    const float* anchors  = (const float*)d_in[2];
    float* out = (float*)d_out;
    char* ws = (char*)d_ws;

    u32* hist     = (u32*)(ws + HIST_OFF);
    u32* counter  = (u32*)(ws + CNT_OFF);
    u32* pB       = (u32*)(ws + B_OFF);
    u64* vwords   = (u64*)(ws + VW_OFF);
    u64* cand     = (u64*)(ws + CAND_OFF);
    float* sc_all = (float*)(ws + SC_OFF);
    int* cls_all  = (int*)(ws + CLS_OFF);
    float* sel_sc = (float*)(ws + SSC_OFF);
    int* sel_cls  = (int*)(ws + SCLS_OFF);
    u64* sup      = (u64*)(ws + SUP_OFF);

    hipMemsetAsync(d_ws, 0, ZERO_BYTES, stream);

    int nb1 = (M_ANCH * 4) / 256;   /* 5625 blocks, 4 lanes per anchor */
    int nbc = (M_ANCH + 255) / 256;
    k_score<<<nb1, 256, 0, stream>>>(cls_pred, sc_all, cls_all, hist);
    k_scan<<<1, 1024, 0, stream>>>(hist, pB);
    k_compact<<<nbc, 256, 0, stream>>>(sc_all, pB, counter, cand);
    k_select<<<1, 1024, 0, stream>>>(cand, counter, sc_all, cls_all, reg_pred,
                                     anchors, out, sel_sc, sel_cls, vwords);
    k_supmat<<<(KTOP * 16) / 4, 256, 0, stream>>>(out, sel_cls, sup);
    k_nms<<<1, 64, 0, stream>>>(sup, vwords, sel_sc, out);
}

// Round 4
// 341.104 us; speedup vs baseline: 1.3704x; 1.3704x over previous
//
#include <hip/hip_runtime.h>
#include <math.h>

typedef unsigned long long u64;
typedef unsigned int u32;

#define M_ANCH 360000
#define NCLS 80
#define KTOP 1000
#define CAP 8192
#define NBINS 65536
#define RREP 8
#define CONF_THRESH 0.05f
#define NMS_THRESH 0.6f
#define CTR_CLAMP 32.0f
#define SCALE_CLAMP 4.1351665567423560f  /* log(1000/16) */

/* ---- workspace layout (bytes) ---- */
#define HIST_OFF   0u
#define HIST_BYTES (RREP * NBINS * 4u)            /* 2,097,152 */
#define MERGED_OFF (HIST_OFF + HIST_BYTES)        /* 65536*4 = 262,144 */
#define BLKSUM_OFF (MERGED_OFF + NBINS * 4u)      /* 64*4 = 256 */
#define CNT_OFF    (BLKSUM_OFF + 256u)
#define B_OFF      (CNT_OFF + 4u)
#define VW_OFF     (B_OFF + 4u)                   /* 16 u64 = 128 B (8-aligned) */
#define ZERO_END   (VW_OFF + 128u)
#define CAND_OFF   ZERO_END                       /* 8192 * 8 */
#define SC_OFF     (CAND_OFF + CAP * 8u)          /* M floats */
#define CLS_OFF    (SC_OFF + M_ANCH * 4u)         /* M ints */
#define SSC_OFF    (CLS_OFF + M_ANCH * 4u)        /* 1000 floats */
#define SCLS_OFF   (SSC_OFF + KTOP * 4u)          /* 1000 ints */
#define SUP_OFF    (SCLS_OFF + KTOP * 4u)         /* 16000 u64 */

__device__ __forceinline__ u32 fkey(float f) {
    u32 u = __float_as_uint(f);
    return (u & 0x80000000u) ? ~u : (u | 0x80000000u);
}

/* K1: block owns 64 anchors = 1280 contiguous float4s = 20 KB.
   Phase 1: 5 block-stride float4 loads (perfectly coalesced: lane i reads
   base + 16*i, 1 KB per wave-instruction), per-float4 max -> LDS with
   stride-21 padding (odd stride -> conflict-free).
   Phase 2: 64 threads reduce 20 slots each (strict > keeps lowest class). */
__global__ __launch_bounds__(256) void k_score(const float* __restrict__ cls_pred,
                                               float* __restrict__ sc_all,
                                               int* __restrict__ cls_all,
                                               u32* __restrict__ hist) {
    __shared__ float lm[64 * 21];
    __shared__ int   lc[64 * 21];
    int t = threadIdx.x;
    const float4* p = (const float4*)cls_pred + (size_t)blockIdx.x * 1280;
    float4 v0 = p[t];
    float4 v1 = p[t + 256];
    float4 v2 = p[t + 512];
    float4 v3 = p[t + 768];
    float4 v4 = p[t + 1024];
#pragma unroll
    for (int k = 0; k < 5; k++) {
        float4 v = (k == 0) ? v0 : (k == 1) ? v1 : (k == 2) ? v2 : (k == 3) ? v3 : v4;
        int f = t + 256 * k;      /* [0, 1280) */
        int a = f / 20;           /* local anchor [0, 64) */
        int s = f % 20;           /* slot [0, 20) */
        float mv = v.x; int mc = 0;
        if (v.y > mv) { mv = v.y; mc = 1; }
        if (v.z > mv) { mv = v.z; mc = 2; }
        if (v.w > mv) { mv = v.w; mc = 3; }
        lm[a * 21 + s] = mv;
        lc[a * 21 + s] = s * 4 + mc;
    }
    __syncthreads();
    if (t < 64) {
        float mv = -1e30f; int mc = 0;
#pragma unroll
        for (int s = 0; s < 20; s++) {
            float m = lm[t * 21 + s];
            int c = lc[t * 21 + s];
            if (m > mv) { mv = m; mc = c; }
        }
        int a = blockIdx.x * 64 + t;
        float sc = 1.0f / (1.0f + expf(-mv));
        sc_all[a] = sc;
        cls_all[a] = mc;
        float msk = (sc >= CONF_THRESH) ? sc : -1.0f;
        u32 u = fkey(msk);
        atomicAdd(&hist[((blockIdx.x & (RREP - 1)) << 16) + (u >> 16)], 1u);
    }
}

/* K2a: merge RREP histogram replicas (coalesced), emit per-1024-bin block sums */
__global__ __launch_bounds__(1024) void k_hsum(const u32* __restrict__ hist,
                                               u32* __restrict__ merged,
                                               u32* __restrict__ blksum) {
    __shared__ u32 red[1024];
    int t = threadIdx.x;
    int b = blockIdx.x * 1024 + t;
    u32 s = 0;
#pragma unroll
    for (int r = 0; r < RREP; r++) s += hist[r * NBINS + b];
    merged[b] = s;
    red[t] = s;
    __syncthreads();
    for (int off = 512; off > 0; off >>= 1) {
        if (t < off) red[t] += red[t + off];
        __syncthreads();
    }
    if (t == 0) blksum[blockIdx.x] = red[0];
}

/* K2b: find boundary bin B = max b with count(bins >= b) >= KTOP */
__global__ __launch_bounds__(1024) void k_boundary(const u32* __restrict__ merged,
                                                   const u32* __restrict__ blksum,
                                                   u32* __restrict__ outB) {
    __shared__ u32 bs[64];
    __shared__ u32 sj, sA;
    __shared__ u32 csum[1024];
    int t = threadIdx.x;
    if (t < 64) bs[t] = blksum[t];
    __syncthreads();
    if (t == 0) {
        u32 cum = 0; u32 j = 0; u32 Aj = 0;
        for (int b = 63; b >= 0; b--) {
            if (cum + bs[b] >= KTOP) { j = (u32)b; Aj = cum; break; }
            cum += bs[b];
        }
        sj = j; sA = Aj;
    }
    __syncthreads();
    u32 j = sj, Aj = sA;
    u32 h = merged[j * 1024 + t];
    csum[t] = h;
    __syncthreads();
    u32 v = h;
    for (int off = 1; off < 1024; off <<= 1) {
        u32 add = (t + off < 1024) ? csum[t + off] : 0u;
        __syncthreads();
        v += add;
        csum[t] = v;
        __syncthreads();
    }
    u32 above = (t == 1023) ? 0u : csum[t + 1];
    if (Aj + above < KTOP && Aj + above + h >= KTOP) outB[0] = j * 1024 + t;
}

/* K3: compact candidates (key bin >= B). Candidate SET is deterministic;
   order is not, but K4 sorts. CAP=8192 gives wide overflow margin. */
__global__ __launch_bounds__(256) void k_compact(const float* __restrict__ sc_all,
                                                 const u32* __restrict__ pB,
                                                 u32* __restrict__ counter,
                                                 u64* __restrict__ cand) {
    int i = blockIdx.x * 256 + threadIdx.x;
    if (i >= M_ANCH) return;
    u32 B = *pB;
    float s = sc_all[i];
    float m = (s >= CONF_THRESH) ? s : -1.0f;
    u32 u = fkey(m);
    if ((u >> 16) >= B) {
        u32 pos = atomicAdd(counter, 1u);
        if (pos < CAP) cand[pos] = ((u64)u << 32) | (u64)(0xFFFFFFFFu - (u32)i);
    }
}

/* K4: adaptive bitonic sort (P = next pow2 >= n, min 1024), top 1000, decode */
__global__ __launch_bounds__(1024) void k_select(const u64* __restrict__ cand,
                                                 const u32* __restrict__ counter,
                                                 const float* __restrict__ sc_all,
                                                 const int* __restrict__ cls_all,
                                                 const float* __restrict__ reg_pred,
                                                 const float* __restrict__ anchors,
                                                 float* __restrict__ out,
                                                 float* __restrict__ sel_sc,
                                                 int* __restrict__ sel_cls,
                                                 u64* __restrict__ valid_words) {
    __shared__ u64 keys[CAP];
    int t = threadIdx.x;
    u32 n = *counter;
    if (n > CAP) n = CAP;
    u32 P = 1024;
    while (P < n) P <<= 1;            /* P in {1024,...,8192} */
    for (u32 i = t; i < P; i += 1024) keys[i] = (i < n) ? cand[i] : 0ull;
    for (u32 k = 2; k <= P; k <<= 1) {
        for (u32 j = k >> 1; j > 0; j >>= 1) {
            __syncthreads();
            for (u32 i = t; i < P; i += 1024) {
                u32 ixj = i ^ j;
                if (ixj > i) {
                    u64 a = keys[i], b = keys[ixj];
                    bool desc = ((i & k) == 0);
                    if (desc ? (a < b) : (a > b)) { keys[i] = b; keys[ixj] = a; }
                }
            }
        }
    }
    __syncthreads();
    if (t < KTOP) {
        u64 key = keys[t];
        u32 idx = 0xFFFFFFFFu - (u32)(key & 0xFFFFFFFFull);
        if (idx >= M_ANCH) idx = 0;
        float s = sc_all[idx];
        int cl = cls_all[idx];
        float4 a = ((const float4*)anchors)[idx];
        float4 r = ((const float4*)reg_pred)[idx];
        float ox = fminf(fmaxf(r.x * a.z, -CTR_CLAMP), CTR_CLAMP);
        float oy = fminf(fmaxf(r.y * a.w, -CTR_CLAMP), CTR_CLAMP);
        float cx = a.x + ox, cy = a.y + oy;
        float ww = a.z * expf(fminf(r.z, SCALE_CLAMP));
        float hh = a.w * expf(fminf(r.w, SCALE_CLAMP));
        float4 box;
        box.x = cx - 0.5f * ww;
        box.y = cy - 0.5f * hh;
        box.z = cx + 0.5f * ww;
        box.w = cy + 0.5f * hh;
        ((float4*)out)[t] = box;                 /* boxes: out[0..3999] */
        out[5 * KTOP + t] = (float)cl;           /* classes: out[5000..5999] */
        sel_sc[t] = s;
        sel_cls[t] = cl;
        if (s >= CONF_THRESH) atomicOr(&valid_words[t >> 6], 1ull << (t & 63));
    }
}

/* K5: suppression matrix — one wave computes one 64-wide word via ballot */
__global__ __launch_bounds__(256) void k_supmat(const float* __restrict__ out,
                                                const int* __restrict__ sel_cls,
                                                u64* __restrict__ sup) {
    int wid = threadIdx.x >> 6;
    int lane = threadIdx.x & 63;
    int g = blockIdx.x * 4 + wid;          /* g in [0, 16000) */
    int i = g >> 4;
    int w = g & 15;
    int j = w * 64 + lane;
    int jc = (j < KTOP) ? j : (KTOP - 1);
    float4 bi = ((const float4*)out)[i];
    float4 bj = ((const float4*)out)[jc];
    int ci = sel_cls[i], cj = sel_cls[jc];
    float ai = (bi.z - bi.x) * (bi.w - bi.y);
    float aj = (bj.z - bj.x) * (bj.w - bj.y);
    float xx1 = fmaxf(bi.x, bj.x), yy1 = fmaxf(bi.y, bj.y);
    float xx2 = fminf(bi.z, bj.z), yy2 = fminf(bi.w, bj.w);
    float iw = fmaxf(1e-28f, xx2 - xx1), ih = fmaxf(1e-28f, yy2 - yy1);
    float inter = iw * ih;
    float iou = inter / (ai + aj - inter + 1e-14f);
    bool pred = (j < i) && (ci == cj) && (iou > NMS_THRESH);
    u64 bal = __ballot((int)pred);
    if (lane == 0) sup[g] = bal;
}

/* K6: sequential greedy NMS scan, single wave; 16 lanes hold keep-mask words */
#define LOADC(cidx, buf)                                                         \
    {                                                                            \
        _Pragma("unroll") for (int r = 0; r < 16; r++) {                         \
            int row = (cidx)*16 + r;                                             \
            buf[r] = (active && row < KTOP) ? sup[row * 16 + lane] : 0ull;       \
        }                                                                        \
    }

#define PROCC(cidx, buf)                                                         \
    {                                                                            \
        _Pragma("unroll") for (int r = 0; r < 16; r++) {                         \
            int i = (cidx)*16 + r;                                               \
            if (i < KTOP) {                                                      \
                u64 x = buf[r] & keepw;                                          \
                int anysup = __any(x != 0ull);                                   \
                u64 vwv = vws[i >> 6];                                           \
                int vi = (int)((vwv >> (i & 63)) & 1ull);                        \
                int ki = (!anysup) && vi;                                        \
                if (lane == (i >> 6) && ki) keepw |= (1ull << (i & 63));         \
            }                                                                    \
        }                                                                        \
    }

__global__ __launch_bounds__(64) void k_nms(const u64* __restrict__ sup,
                                            const u64* __restrict__ valid_words,
                                            const float* __restrict__ sel_sc,
                                            float* __restrict__ out) {
    __shared__ u64 vws[16];
    __shared__ u64 kw[16];
    int lane = threadIdx.x;
    bool active = lane < 16;
    if (active) vws[lane] = valid_words[lane];
    __syncthreads();
    u64 keepw = 0ull;
    u64 bufA[16], bufB[16];
    const int nChunks = (KTOP + 15) / 16;  /* 63 */
    LOADC(0, bufA);
    for (int c = 0; c < nChunks; c += 2) {
        if (c + 1 < nChunks) LOADC(c + 1, bufB);
        PROCC(c, bufA);
        if (c + 2 < nChunks) LOADC(c + 2, bufA);
        if (c + 1 < nChunks) PROCC(c + 1, bufB);
    }
    if (active) kw[lane] = keepw;
    __syncthreads();
    for (int t = lane; t < KTOP; t += 64) {
        int kb = (int)((kw[t >> 6] >> (t & 63)) & 1ull);
        float s = sel_sc[t];
        out[4 * KTOP + t] = kb ? s : 0.0f;   /* scores*keep: out[4000..4999] */
        out[6 * KTOP + t] = (float)kb;       /* keep:        out[6000..6999] */
    }
}

extern "C" void kernel_launch(void* const* d_in, const int* in_sizes, int n_in,
                              void* d_out, int out_size, void* d_ws, size_t ws_size,
                              hipStream_t stream) {
    const float* cls_pred = (const float*)d_in[0];
    const float* reg_pred = (const float*)d_in[1];
    const float* anchors  = (const float*)d_in[2];
    float* out = (float*)d_out;
    char* ws = (char*)d_ws;

    u32* hist     = (u32*)(ws + HIST_OFF);
    u32* merged   = (u32*)(ws + MERGED_OFF);
    u32* blksum   = (u32*)(ws + BLKSUM_OFF);
    u32* counter  = (u32*)(ws + CNT_OFF);
    u32* pB       = (u32*)(ws + B_OFF);
    u64* vwords   = (u64*)(ws + VW_OFF);
    u64* cand     = (u64*)(ws + CAND_OFF);
    float* sc_all = (float*)(ws + SC_OFF);
    int* cls_all  = (int*)(ws + CLS_OFF);
    float* sel_sc = (float*)(ws + SSC_OFF);
    int* sel_cls  = (int*)(ws + SCLS_OFF);
    u64* sup      = (u64*)(ws + SUP_OFF);

    hipMemsetAsync(d_ws, 0, ZERO_END, stream);

    int nbs = M_ANCH / 64;            /* 5625 blocks, 64 anchors each */
    int nbc = (M_ANCH + 255) / 256;
    k_score<<<nbs, 256, 0, stream>>>(cls_pred, sc_all, cls_all, hist);
    k_hsum<<<NBINS / 1024, 1024, 0, stream>>>(hist, merged, blksum);
    k_boundary<<<1, 1024, 0, stream>>>(merged, blksum, pB);
    k_compact<<<nbc, 256, 0, stream>>>(sc_all, pB, counter, cand);
    k_select<<<1, 1024, 0, stream>>>(cand, counter, sc_all, cls_all, reg_pred,
                                     anchors, out, sel_sc, sel_cls, vwords);
    k_supmat<<<(KTOP * 16) / 4, 256, 0, stream>>>(out, sel_cls, sup);
    k_nms<<<1, 64, 0, stream>>>(sup, vwords, sel_sc, out);
}